// Round 4
// baseline (33.884 us; speedup 1.0000x reference)
//
#include <hip/hip_runtime.h>

#define HW 16384      // 128*128
#define NCH 128       // channels
#define CCH 16        // channels per block
#define LANG 256
#define NH 128
#define NOP 6

typedef float f4 __attribute__((ext_vector_type(4)));

// Single fused kernel. Each block:
//  1. prologue: computes its batch's 12 coefficients (gamma[k]*wr[k],
//     beta[k]*wr[k]) redundantly via a wave-parallel 2-stage GEMV
//     (Ws is 131 KB -> L2-resident after first touch per XCD).
//  2. streams 16 channels of x -> out with the affine transform.
// sem loads are issued before the prologue so HBM latency hides under it.
__global__ __launch_bounds__(256) void fused_kernel(
    const float* __restrict__ x, const float* __restrict__ lang,
    const float* __restrict__ sem,
    const float* __restrict__ Ws, const float* __restrict__ bs,
    const float* __restrict__ Wg, const float* __restrict__ bg,
    const float* __restrict__ Wb, const float* __restrict__ bb,
    const float* __restrict__ Wr, const float* __restrict__ br,
    float* __restrict__ out) {
  const int b = blockIdx.z;
  const int cbase = blockIdx.y * CCH;
  const int tid = threadIdx.x;
  const int wave = tid >> 6, lane = tid & 63;
  const int pix = (blockIdx.x * 256 + tid) * 4;

  __shared__ float actv[NH];
  __shared__ float cf[14];  // 0..5: g*wr, 6..11: be*wr, 12: sum(wr), 13: br

  // ---- issue sem loads early (independent of the coef prologue) ----
  const float* semb = sem + ((size_t)b * 8 + 2) * HW + pix;
  f4 sv[NOP];
  #pragma unroll
  for (int k = 0; k < NOP; ++k) sv[k] = *(const f4*)(semb + (size_t)k * HW);

  // ---- prologue stage 1: actv[j] = bs[j] + lang[b,:] . Ws[j,:] ----
  const f4 lv = *(const f4*)(lang + b * LANG + lane * 4);
  #pragma unroll 8
  for (int m = 0; m < 32; ++m) {
    const int j = wave * 32 + m;
    const f4 wv = *(const f4*)(Ws + (size_t)j * LANG + lane * 4);
    float p = lv.x * wv.x + lv.y * wv.y + lv.z * wv.z + lv.w * wv.w;
    #pragma unroll
    for (int off = 32; off; off >>= 1) p += __shfl_xor(p, off);
    if (lane == 0) actv[j] = p + bs[j];
  }
  __syncthreads();

  // ---- prologue stage 2: 12 dots of length 128, 3 per wave ----
  const float a0 = actv[lane * 2], a1 = actv[lane * 2 + 1];
  #pragma unroll
  for (int r = 0; r < 3; ++r) {
    const int k = wave + 4 * r;              // 0..11
    const int kk = (k < NOP) ? k : k - NOP;  // row in Wg/Wb
    const float* W = ((k < NOP) ? Wg : Wb) + kk * NH;
    float p = a0 * W[lane * 2] + a1 * W[lane * 2 + 1];
    #pragma unroll
    for (int off = 32; off; off >>= 1) p += __shfl_xor(p, off);
    if (lane == 0) {
      const float bias = (k < NOP) ? bg[kk] : bb[kk];
      cf[k] = (p + bias) * Wr[kk];
    }
  }
  if (tid == 0) {
    float s = 0.f;
    #pragma unroll
    for (int k = 0; k < NOP; ++k) s += Wr[k];
    cf[12] = s;
    cf[13] = br[0];
  }
  __syncthreads();

  // ---- combine sem with coefficients ----
  const float wrsum = cf[12], brv = cf[13];
  f4 scale = {wrsum, wrsum, wrsum, wrsum};
  f4 shift = {brv, brv, brv, brv};
  #pragma unroll
  for (int k = 0; k < NOP; ++k) {
    scale += cf[k] * sv[k];
    shift += cf[NOP + k] * sv[k];
  }

  // ---- stream 16 channels ----
  const size_t base = ((size_t)b * NCH + cbase) * HW + pix;
  const float* xb = x + base;
  float* ob = out + base;
  #pragma unroll
  for (int c = 0; c < CCH; ++c) {
    const f4 v = *(const f4*)(xb + (size_t)c * HW);
    *(f4*)(ob + (size_t)c * HW) = v * scale + shift;
  }
}

extern "C" void kernel_launch(void* const* d_in, const int* in_sizes, int n_in,
                              void* d_out, int out_size, void* d_ws, size_t ws_size,
                              hipStream_t stream) {
  const float* x    = (const float*)d_in[0];
  const float* lang = (const float*)d_in[1];
  const float* sem  = (const float*)d_in[2];
  const float* Ws   = (const float*)d_in[3];
  const float* bs   = (const float*)d_in[4];
  const float* Wg   = (const float*)d_in[5];
  const float* bg   = (const float*)d_in[6];
  const float* Wb   = (const float*)d_in[7];
  const float* bb   = (const float*)d_in[8];
  const float* Wr   = (const float*)d_in[9];
  const float* br   = (const float*)d_in[10];
  float* out = (float*)d_out;

  dim3 grid(HW / (256 * 4), NCH / CCH, 4);  // (16, 8, 4) = 512 blocks
  fused_kernel<<<grid, dim3(256), 0, stream>>>(x, lang, sem, Ws, bs, Wg, bg,
                                               Wb, bb, Wr, br, out);
}